// Round 2
// baseline (46.695 us; speedup 1.0000x reference)
//
#include <hip/hip_runtime.h>
#include <hip/hip_cooperative_groups.h>
#include <cmath>

#define B_DIM 64
#define S_DIM 512
#define H_DIM 768
#define MAX_DEPTH 48
#define EPS 1e-7f

namespace cg = cooperative_groups;

// One cooperative dispatch:
//   Phase 1: 1024 waves (256 blocks x 256 thr), each wave computes 3 (b,l)
//            masked log-sigmoid terms into ws[b*MAX_DEPTH + l].
//   grid.sync()
//   Phase 2: block 0, first wave: lane b sums its 48 terms, /len, cross-lane
//            reduce, write -mean.
__global__ __launch_bounds__(256) void kt_fused_kernel(
    const float* __restrict__ outputs,      // (B, S, H) -- only token 0 used
    const float* __restrict__ embedding,    // (N_NODES, H)
    const int*   __restrict__ path_nodes,   // (B, MAX_DEPTH)
    const int*   __restrict__ path_signs,   // (B, MAX_DEPTH)
    const int*   __restrict__ path_lengths, // (B,)
    float*       __restrict__ terms,        // (B*MAX_DEPTH,) scratch in d_ws
    float*       __restrict__ out)          // scalar
{
    const int lane = threadIdx.x & 63;
    const int wave = (blockIdx.x * blockDim.x + threadIdx.x) >> 6;  // 0..1023

    #pragma unroll
    for (int t = 0; t < 3; ++t) {
        const int idx = wave * 3 + t;       // 0 .. 3071
        const int b   = idx / MAX_DEPTH;
        const int l   = idx % MAX_DEPTH;

        const int len = path_lengths[b];
        float term = 0.0f;
        if (l < len) {
            const int node = path_nodes[idx];
            const float4* __restrict__ e4 =
                (const float4*)(embedding + (size_t)node * H_DIM);
            const float4* __restrict__ h4 =
                (const float4*)(outputs + (size_t)b * S_DIM * H_DIM);

            float acc = 0.0f;
            #pragma unroll
            for (int i = 0; i < 3; ++i) {
                const int j = lane + i * 64;
                float4 a = e4[j];
                float4 c = h4[j];
                acc += a.x * c.x + a.y * c.y + a.z * c.z + a.w * c.w;
            }
            #pragma unroll
            for (int off = 32; off > 0; off >>= 1)
                acc += __shfl_down(acc, off, 64);

            // acc is the full dot only on lane 0; other lanes compute junk here,
            // but only lane 0 stores.
            const float sgn = (float)(2 * path_signs[idx] - 1);
            const float x   = sgn * acc;
            const float sig = 1.0f / (1.0f + __expf(-x));
            term = __logf(sig + EPS);
        }
        if (lane == 0) terms[idx] = term;
    }

    cg::this_grid().sync();

    if (blockIdx.x == 0 && threadIdx.x < 64) {
        const int b = threadIdx.x;          // 0..63 == B_DIM-1
        float s = 0.0f;
        #pragma unroll
        for (int l = 0; l < MAX_DEPTH; ++l)
            s += terms[b * MAX_DEPTH + l];
        s /= (float)path_lengths[b];

        #pragma unroll
        for (int off = 32; off > 0; off >>= 1)
            s += __shfl_down(s, off, 64);

        if (b == 0) out[0] = -s / (float)B_DIM;
    }
}

extern "C" void kernel_launch(void* const* d_in, const int* in_sizes, int n_in,
                              void* d_out, int out_size, void* d_ws, size_t ws_size,
                              hipStream_t stream) {
    const float* outputs      = (const float*)d_in[0];
    const float* embedding    = (const float*)d_in[1];
    const int*   path_nodes   = (const int*)d_in[2];
    const int*   path_signs   = (const int*)d_in[3];
    const int*   path_lengths = (const int*)d_in[4];
    float*       out          = (float*)d_out;
    float*       terms        = (float*)d_ws;   // B*MAX_DEPTH floats = 12 KiB

    void* args[] = { (void*)&outputs, (void*)&embedding, (void*)&path_nodes,
                     (void*)&path_signs, (void*)&path_lengths,
                     (void*)&terms, (void*)&out };
    hipLaunchCooperativeKernel((void*)kt_fused_kernel,
                               dim3(256), dim3(256), args, 0, stream);
}

// Round 3
// 14.060 us; speedup vs baseline: 3.3212x; 3.3212x over previous
//
#include <hip/hip_runtime.h>
#include <cmath>

#define B_DIM 64
#define S_DIM 512
#define H_DIM 768
#define MAX_DEPTH 48
#define EPS 1e-7f

// Single dispatch: 256 blocks x 256 threads = 1024 waves; each wave computes
// 3 of the 3072 (b,l) masked log-sigmoid terms, pre-scaled by -1/(len_b*B),
// block-reduces 4 wave partials in LDS, one atomicAdd per block into out[0].
// out[0] is zeroed by a memset node before the kernel node.
__global__ __launch_bounds__(256) void kt_fused_atomic_kernel(
    const float* __restrict__ outputs,      // (B, S, H) -- only token 0 used
    const float* __restrict__ embedding,    // (N_NODES, H)
    const int*   __restrict__ path_nodes,   // (B, MAX_DEPTH)
    const int*   __restrict__ path_signs,   // (B, MAX_DEPTH)
    const int*   __restrict__ path_lengths, // (B,)
    float*       __restrict__ out)          // scalar accumulator (pre-zeroed)
{
    const int lane = threadIdx.x & 63;
    const int wid  = threadIdx.x >> 6;               // 0..3
    const int wave = blockIdx.x * 4 + wid;           // 0..1023
    __shared__ float partial[4];

    float wsum = 0.0f;                               // meaningful on lane 0 only
    #pragma unroll
    for (int t = 0; t < 3; ++t) {
        const int idx = wave * 3 + t;                // 0 .. 3071
        const int b   = idx / MAX_DEPTH;
        const int l   = idx % MAX_DEPTH;
        const int len = path_lengths[b];
        if (l < len) {
            const int node = path_nodes[idx];
            const float4* __restrict__ e4 =
                (const float4*)(embedding + (size_t)node * H_DIM);
            const float4* __restrict__ h4 =
                (const float4*)(outputs + (size_t)b * S_DIM * H_DIM);

            float acc = 0.0f;
            #pragma unroll
            for (int i = 0; i < 3; ++i) {
                const int j = lane + i * 64;
                float4 a = e4[j];
                float4 c = h4[j];
                acc += a.x * c.x + a.y * c.y + a.z * c.z + a.w * c.w;
            }
            #pragma unroll
            for (int off = 32; off > 0; off >>= 1)
                acc += __shfl_down(acc, off, 64);

            if (lane == 0) {
                const float sgn  = (float)(2 * path_signs[idx] - 1);
                const float x    = sgn * acc;
                const float sig  = 1.0f / (1.0f + __expf(-x));
                const float term = __logf(sig + EPS);
                wsum += term * (-1.0f / ((float)len * (float)B_DIM));
            }
        }
    }
    if (lane == 0) partial[wid] = wsum;
    __syncthreads();
    if (threadIdx.x == 0) {
        atomicAdd(out, partial[0] + partial[1] + partial[2] + partial[3]);
    }
}

extern "C" void kernel_launch(void* const* d_in, const int* in_sizes, int n_in,
                              void* d_out, int out_size, void* d_ws, size_t ws_size,
                              hipStream_t stream) {
    const float* outputs      = (const float*)d_in[0];
    const float* embedding    = (const float*)d_in[1];
    const int*   path_nodes   = (const int*)d_in[2];
    const int*   path_signs   = (const int*)d_in[3];
    const int*   path_lengths = (const int*)d_in[4];
    float*       out          = (float*)d_out;

    hipMemsetAsync(out, 0, sizeof(float), stream);   // capturable memset node
    kt_fused_atomic_kernel<<<256, 256, 0, stream>>>(
        outputs, embedding, path_nodes, path_signs, path_lengths, out);
}